// Round 9
// baseline (128.848 us; speedup 1.0000x reference)
//
#include <hip/hip_runtime.h>
#include <hip/hip_bf16.h>

// GCN layer on MI355X.
// out[n] = (segment_sum over edges e with dst[e]==n of w[e]*nodes[src[e]]) @ K
// Linearity: out = segment_sum(w[e] * P[src[e]] -> dst[e]),  P = nodes @ K.
// N=65536, E=1048576 (dst SORTED), D=UNITS=64.
//
// Round-9: wave-per-node CSR aggregation.
//  - build_rowptr: boundaries of the sorted dst array -> row_ptr[N+1] (d_ws).
//  - agg_nodes: ONE WAVE PER NODE (65536 waves, 8x the scatter's TLP; work per
//    wave ~16 edges). Gathers in 8-wide blocks from 4-aligned edge offsets with
//    range-masked weights; single plain store per out row. No atomics, no
//    zero-pass, no run-detection branch. Attacks the measured latency x
//    concurrency bound (scatter was ~46us invariant to bytes & scalarization;
//    only ~22 outstanding gathers/CU = <1/wave).
//  - gemm_rows: lane=unit, K column in VGPRs, A-row via readfirstlane->s_load.
//  - harness's 256MiB d_ws re-poison (~45us) + 16MB out poison (~3us) are inside
//    the timed path - fixed floor.

constexpr int D = 64;
constexpr int EPW = 128;  // fallback scatter only

__global__ __launch_bounds__(256) void zero_kernel(float4* __restrict__ p, int n4) {
    int i = blockIdx.x * blockDim.x + threadIdx.x;
    int stride = gridDim.x * blockDim.x;
    for (; i < n4; i += stride) p[i] = make_float4(0.f, 0.f, 0.f, 0.f);
}

// P_bf16 = bf16(nodes @ K).  One wave per 8 rows; lane = output unit.
// kcol[d] = K[d][lane] lives in VGPRs; A-row comes in through SGPRs (s_load).
__global__ __launch_bounds__(256) void gemm_rows(const float* __restrict__ nodes,
                                                 const float* __restrict__ Km,
                                                 __hip_bfloat16* __restrict__ P,
                                                 int n_nodes) {
    const int lane = threadIdx.x & 63;
    float kcol[D];
    #pragma unroll
    for (int d = 0; d < D; ++d) kcol[d] = Km[d * D + lane];

    const int wid = (blockIdx.x * blockDim.x + threadIdx.x) >> 6;
    const int urow0 = __builtin_amdgcn_readfirstlane(wid * 8);

    #pragma unroll 1
    for (int i = 0; i < 8; ++i) {
        const int row = urow0 + i;                 // uniform
        if (row >= n_nodes) return;
        const float4* rp = (const float4*)(nodes + (long)row * D);  // uniform addr
        float4 a[16];
        #pragma unroll
        for (int q = 0; q < 16; ++q) a[q] = rp[q]; // -> s_load_dwordx16 x4
        const float* af = (const float*)a;
        float acc0 = 0.f, acc1 = 0.f, acc2 = 0.f, acc3 = 0.f;
        #pragma unroll
        for (int d = 0; d < D; d += 4) {
            acc0 = fmaf(af[d + 0], kcol[d + 0], acc0);
            acc1 = fmaf(af[d + 1], kcol[d + 1], acc1);
            acc2 = fmaf(af[d + 2], kcol[d + 2], acc2);
            acc3 = fmaf(af[d + 3], kcol[d + 3], acc3);
        }
        const float acc = (acc0 + acc1) + (acc2 + acc3);
        __hip_bfloat16 b = __float2bfloat16(acc);
        P[(long)row * D + lane] = b;               // coalesced 128B store
    }
}

// row_ptr from sorted dst: rp[n] = first edge with dst >= n; rp[N] = E.
// Each dst-boundary thread writes the gap range (gaps are tiny: E/N = 16).
__global__ __launch_bounds__(256) void build_rowptr(const int* __restrict__ dst,
                                                    int* __restrict__ rp,
                                                    int n_edges, int n_nodes) {
    int e = blockIdx.x * blockDim.x + threadIdx.x;
    const int stride = gridDim.x * blockDim.x;
    for (; e < n_edges; e += stride) {
        const int d = dst[e];
        const int pd = (e == 0) ? -1 : dst[e - 1];
        if (d != pd)
            for (int n = pd + 1; n <= d; ++n) rp[n] = e;
        if (e == n_edges - 1)
            for (int n = d + 1; n <= n_nodes; ++n) rp[n] = n_edges;
    }
}

// One wave per node. lane = feature. Edges [lo,hi) processed in 8-wide blocks
// starting at lo&~3 (int4/float4 16B-aligned); weights masked to [lo,hi).
// Single plain store per row -> no atomics anywhere, no zero-init needed.
__global__ __launch_bounds__(256) void agg_nodes(const __hip_bfloat16* __restrict__ P,
                                                 const float* __restrict__ evals,
                                                 const int* __restrict__ src,
                                                 const int* __restrict__ rp,
                                                 float* __restrict__ out,
                                                 int n_nodes, int n_edges) {
    const int lane = threadIdx.x & 63;
    const int n = (blockIdx.x * blockDim.x + threadIdx.x) >> 6;
    if (n >= n_nodes) return;
    const int lo = __builtin_amdgcn_readfirstlane(rp[n]);
    const int hi = __builtin_amdgcn_readfirstlane(rp[n + 1]);

    float acc = 0.f;
    int e0 = lo & ~3;
    #pragma unroll 1
    while (e0 < hi) {
        if (e0 + 8 <= n_edges) {
            const int4   s0 = *(const int4*)(src + e0);
            const int4   s1 = *(const int4*)(src + e0 + 4);
            const float4 w0 = *(const float4*)(evals + e0);
            const float4 w1 = *(const float4*)(evals + e0 + 4);
            const int   sv[8]   = {s0.x, s0.y, s0.z, s0.w, s1.x, s1.y, s1.z, s1.w};
            const float wraw[8] = {w0.x, w0.y, w0.z, w0.w, w1.x, w1.y, w1.z, w1.w};
            float v[8];
            #pragma unroll
            for (int j = 0; j < 8; ++j) {
                const int sj = __builtin_amdgcn_readfirstlane(sv[j]);  // saddr gather
                v[j] = __bfloat162float(P[(long)sj * D + lane]);
            }
            #pragma unroll
            for (int j = 0; j < 8; ++j) {
                const int e = e0 + j;
                const float w = (e >= lo && e < hi) ? wraw[j] : 0.f;  // uniform mask
                acc = fmaf(w, v[j], acc);
            }
            e0 += 8;
        } else {
            // final partial block of the edge array (last node only)
            for (int e = (e0 > lo ? e0 : lo); e < hi; ++e) {
                const int sj = __builtin_amdgcn_readfirstlane(src[e]);
                acc = fmaf(evals[e], __bfloat162float(P[(long)sj * D + lane]), acc);
            }
            break;
        }
    }
    out[(long)n * D + lane] = acc;   // exactly one writer per row (also zeros empties)
}

// ---------------- fallback path (d_ws too small): f32 scatter + projection ----
template <typename T>
__device__ __forceinline__ float load_feat(const T* P, long idx);
template <>
__device__ __forceinline__ float load_feat<float>(const float* P, long idx) { return P[idx]; }

__global__ __launch_bounds__(256) void scatter_sorted_f32(
    const float* __restrict__ P, const float* __restrict__ evals,
    const int* __restrict__ src, const int* __restrict__ dst,
    float* __restrict__ out, int n_edges)
{
    const int lane = threadIdx.x & 63;
    const int wid  = blockIdx.x * (blockDim.x >> 6) + (threadIdx.x >> 6);
    const long base = (long)wid * EPW;
    if (base >= n_edges) return;
    const int ubase = __builtin_amdgcn_readfirstlane((int)base);

    const int first = dst[ubase];
    int prev = first;
    float acc = 0.f;

    #pragma unroll 1
    for (int i0 = 0; i0 < EPW && ubase + i0 < n_edges; i0 += 1) {
        const long e = ubase + i0;
        int s = src[e], dc = dst[e]; float w = evals[e];
        float v = P[(long)s * D + lane];
        if (dc != prev) {
            float* o = &out[(long)prev * D + lane];
            if (prev == first) atomicAdd(o, acc);
            else               *o = acc;
            acc = 0.f;
            prev = dc;
        }
        acc = fmaf(w, v, acc);
    }
    atomicAdd(&out[(long)prev * D + lane], acc);
}

__global__ __launch_bounds__(256) void project_inplace(float* __restrict__ out,
                                                       const float* __restrict__ Km, int n_nodes) {
    __shared__ float Ks[D * D];
    const int t = threadIdx.x;
    for (int i = t; i < D * D; i += 256) Ks[i] = Km[i];
    __syncthreads();
    const int lane = t & 63;
    const int n = blockIdx.x * 4 + (t >> 6);
    if (n >= n_nodes) return;
    float* row = out + (long)n * D;
    const float rv = row[lane];
    float acc = 0.f;
    #pragma unroll
    for (int d = 0; d < D; ++d) acc = fmaf(__shfl(rv, d), Ks[d * D + lane], acc);
    row[lane] = acc;
}

extern "C" void kernel_launch(void* const* d_in, const int* in_sizes, int n_in,
                              void* d_out, int out_size, void* d_ws, size_t ws_size,
                              hipStream_t stream) {
    const float* nodes = (const float*)d_in[0];
    const float* evals = (const float*)d_in[1];
    const float* Km    = (const float*)d_in[2];
    const int*   src   = (const int*)d_in[3];
    const int*   dst   = (const int*)d_in[4];
    float* out = (float*)d_out;

    const int n_nodes = in_sizes[0] / D;
    const int n_edges = in_sizes[1];

    const size_t p_bytes  = (size_t)n_nodes * D * sizeof(__hip_bfloat16);
    const size_t rp_bytes = (size_t)(n_nodes + 1) * sizeof(int);

    if (ws_size >= p_bytes + rp_bytes) {
        __hip_bfloat16* P = (__hip_bfloat16*)d_ws;
        int* rp = (int*)((char*)d_ws + p_bytes);

        build_rowptr<<<2048, 256, 0, stream>>>(dst, rp, n_edges, n_nodes);
        const int gw = (n_nodes + 7) / 8;
        gemm_rows<<<(gw + 3) / 4, 256, 0, stream>>>(nodes, Km, P, n_nodes);
        agg_nodes<<<(n_nodes + 3) / 4, 256, 0, stream>>>(P, evals, src, rp, out,
                                                         n_nodes, n_edges);
    } else {
        zero_kernel<<<2048, 256, 0, stream>>>((float4*)out, out_size / 4);
        const int n_waves = (n_edges + EPW - 1) / EPW;
        scatter_sorted_f32<<<(n_waves + 3) / 4, 256, 0, stream>>>(
            nodes, evals, src, dst, out, n_edges);
        project_inplace<<<(n_nodes + 3) / 4, 256, 0, stream>>>(out, Km, n_nodes);
    }
}

// Round 10
// 122.465 us; speedup vs baseline: 1.0521x; 1.0521x over previous
//
#include <hip/hip_runtime.h>
#include <hip/hip_bf16.h>

// GCN layer on MI355X.
// out[n] = (segment_sum over edges e with dst[e]==n of w[e]*nodes[src[e]]) @ K
// Linearity: out = segment_sum(w[e] * P[src[e]] -> dst[e]),  P = nodes @ K.
// N=65536, E=1048576 (dst SORTED), D=UNITS=64.
//
// Round-10: VMEM-instruction reduction (measured bound: time tracks VMEM instr
// count, invariant to gather bytes [r4 vs r6] and wave count [r9]).
//  - scatter_packed: 4 edges PER GATHER INSTRUCTION (16 lanes/edge, uint2 = 4
//    bf16 feats/lane); edge stream loaded coalesced (3 VMEM per 64 edges) and
//    redistributed via shfl (DS pipe); run boundaries via one ballot bitmap;
//    flush = shfl_xor cross-group reduce + 1 dword store/atomic per lane.
//    VMEM per 64 edges: ~23 vs ~112 in round 6.
//  - interior runs = plain store (exclusive ownership from sorted dst),
//    boundary runs (first of chunk / epilogue) = atomicAdd onto zeroed out.
//  - gemm_rows: lane=unit, K col in VGPRs, A-row via readfirstlane->s_load.
//  - harness re-poison fills (~48us: 256MiB d_ws + 16MB out) are in the timed
//    path - fixed floor.

constexpr int D = 64;
constexpr int EPW = 128;  // edges per wave (8192 waves)

__global__ __launch_bounds__(256) void zero_kernel(float4* __restrict__ p, int n4) {
    int i = blockIdx.x * blockDim.x + threadIdx.x;
    int stride = gridDim.x * blockDim.x;
    for (; i < n4; i += stride) p[i] = make_float4(0.f, 0.f, 0.f, 0.f);
}

// P_bf16 = bf16(nodes @ K).  One wave per 8 rows; lane = output unit.
__global__ __launch_bounds__(256) void gemm_rows(const float* __restrict__ nodes,
                                                 const float* __restrict__ Km,
                                                 ushort* __restrict__ P,
                                                 int n_nodes) {
    const int lane = threadIdx.x & 63;
    float kcol[D];
    #pragma unroll
    for (int d = 0; d < D; ++d) kcol[d] = Km[d * D + lane];

    const int wid = (blockIdx.x * blockDim.x + threadIdx.x) >> 6;
    const int urow0 = __builtin_amdgcn_readfirstlane(wid * 8);

    #pragma unroll 1
    for (int i = 0; i < 8; ++i) {
        const int row = urow0 + i;                 // uniform
        if (row >= n_nodes) return;
        const float4* rp = (const float4*)(nodes + (long)row * D);  // uniform addr
        float4 a[16];
        #pragma unroll
        for (int q = 0; q < 16; ++q) a[q] = rp[q]; // -> s_load
        const float* af = (const float*)a;
        float acc0 = 0.f, acc1 = 0.f, acc2 = 0.f, acc3 = 0.f;
        #pragma unroll
        for (int d = 0; d < D; d += 4) {
            acc0 = fmaf(af[d + 0], kcol[d + 0], acc0);
            acc1 = fmaf(af[d + 1], kcol[d + 1], acc1);
            acc2 = fmaf(af[d + 2], kcol[d + 2], acc2);
            acc3 = fmaf(af[d + 3], kcol[d + 3], acc3);
        }
        const float acc = (acc0 + acc1) + (acc2 + acc3);
        __hip_bfloat16 b = __float2bfloat16(acc);
        P[(long)row * D + lane] = *(ushort*)&b;    // coalesced 128B store
    }
}

// select a.{x,y,z,w} by runtime g without scratch (cndmask chain)
__device__ __forceinline__ float sel4(int g, float4 a) {
    float v01 = (g & 1) ? a.y : a.x;
    float v23 = (g & 1) ? a.w : a.z;
    return (g & 2) ? v23 : v01;
}

// cross-group (4x16 lanes) reduce of acc, then one dword per lane:
// lane (g,f) writes out[prev*64 + 4f + g] = sum_groups acc[g-th elem].
__device__ __forceinline__ void flush_run(float* __restrict__ out, int prev,
                                          bool use_atomic, float4& acc,
                                          int f, int g) {
    float4 a = acc;
    a.x += __shfl_xor(a.x, 16); a.x += __shfl_xor(a.x, 32);
    a.y += __shfl_xor(a.y, 16); a.y += __shfl_xor(a.y, 32);
    a.z += __shfl_xor(a.z, 16); a.z += __shfl_xor(a.z, 32);
    a.w += __shfl_xor(a.w, 16); a.w += __shfl_xor(a.w, 32);
    const float val = sel4(g, a);
    float* p = out + (long)prev * D + f * 4 + g;
    if (use_atomic) atomicAdd(p, val);
    else            *p = val;
    acc = make_float4(0.f, 0.f, 0.f, 0.f);
}

// One wave per EPW-edge chunk. Lane (g = lane>>4, f = lane&15): edge-group g,
// feature quad 4f..4f+3. Per 64 edges: 3 coalesced stream loads + 16 packed
// gathers (4 edges each). dst sorted -> ballot boundary bitmap, scalar tests.
__global__ __launch_bounds__(256) void scatter_packed(
    const ushort* __restrict__ P, const float* __restrict__ evals,
    const int* __restrict__ src, const int* __restrict__ dst,
    float* __restrict__ out, int n_edges)
{
    const int lane = threadIdx.x & 63;
    const int g = lane >> 4;
    const int f = lane & 15;
    const int wid = blockIdx.x * (blockDim.x >> 6) + (threadIdx.x >> 6);
    const long base = (long)wid * EPW;
    if (base >= n_edges) return;

    if (base + EPW <= n_edges) {
        const int first = dst[base];
        int prev = first;
        float4 acc = make_float4(0.f, 0.f, 0.f, 0.f);

        #pragma unroll 1
        for (int i0 = 0; i0 < EPW; i0 += 64) {
            const long eb = base + i0;
            const int   sl = src[eb + lane];     // coalesced 256B
            const int   dl = dst[eb + lane];     // coalesced 256B
            const float wl = evals[eb + lane];   // coalesced 256B

            // run-boundary bitmap: bit l set iff edge eb+l starts a new run
            const int dpv = __shfl_up(dl, 1);
            const bool bnd = (lane == 0) ? (dl != prev) : (dl != dpv);
            const unsigned long long bmask = __ballot(bnd);

            // issue all 16 packed gathers (4 rows per instruction)
            uint2 v[16];
            #pragma unroll
            for (int u = 0; u < 16; ++u) {
                const int row = __shfl(sl, 4 * u + g);        // my edge's src row
                v[u] = *(const uint2*)(P + (long)row * D + f * 4);  // 8B: 4 bf16
            }

            #pragma unroll
            for (int u = 0; u < 16; ++u) {
                const float wme = __shfl(wl, 4 * u + g);      // my edge's weight
                float4 pv;
                pv.x = __uint_as_float(v[u].x << 16);
                pv.y = __uint_as_float(v[u].x & 0xffff0000u);
                pv.z = __uint_as_float(v[u].y << 16);
                pv.w = __uint_as_float(v[u].y & 0xffff0000u);
                const unsigned bb = (unsigned)((bmask >> (4 * u)) & 0xFull);
                if (bb == 0u) {                               // scalar branch
                    acc.x = fmaf(wme, pv.x, acc.x);
                    acc.y = fmaf(wme, pv.y, acc.y);
                    acc.z = fmaf(wme, pv.z, acc.z);
                    acc.w = fmaf(wme, pv.w, acc.w);
                } else {
                    // boundary block: per-edge, flush at each new run
                    #pragma unroll
                    for (int k = 0; k < 4; ++k) {
                        if ((bb >> k) & 1u) {                 // scalar branch
                            flush_run(out, prev, prev == first, acc, f, g);
                            prev = __shfl(dl, 4 * u + k);     // uniform
                        }
                        const float wk = (g == k) ? wme : 0.f;
                        acc.x = fmaf(wk, pv.x, acc.x);
                        acc.y = fmaf(wk, pv.y, acc.y);
                        acc.z = fmaf(wk, pv.z, acc.z);
                        acc.w = fmaf(wk, pv.w, acc.w);
                    }
                }
            }
        }
        flush_run(out, prev, true, acc, f, g);   // run may continue in next chunk
    } else {
        // tail chunk (unused when EPW | n_edges): lane = feature, per-edge atomic
        for (long e = base; e < n_edges; ++e) {
            const int s = src[e];
            const float w = evals[e];
            const float pvf = __uint_as_float(((unsigned)P[(long)s * D + lane]) << 16);
            atomicAdd(&out[(long)dst[e] * D + lane], w * pvf);
        }
    }
}

// ---------------- fallback path (d_ws too small): f32 scatter + projection ----
__global__ __launch_bounds__(256) void scatter_simple_f32(
    const float* __restrict__ nodes, const float* __restrict__ evals,
    const int* __restrict__ src, const int* __restrict__ dst,
    float* __restrict__ out, int n_edges)
{
    const int lane = threadIdx.x & 63;
    const int wid  = blockIdx.x * (blockDim.x >> 6) + (threadIdx.x >> 6);
    const long base = (long)wid * EPW;
    if (base >= n_edges) return;
    long end = base + EPW; if (end > n_edges) end = n_edges;
    for (long e = base; e < end; ++e)
        atomicAdd(&out[(long)dst[e] * D + lane], evals[e] * nodes[(long)src[e] * D + lane]);
}

__global__ __launch_bounds__(256) void project_inplace(float* __restrict__ out,
                                                       const float* __restrict__ Km, int n_nodes) {
    __shared__ float Ks[D * D];
    const int t = threadIdx.x;
    for (int i = t; i < D * D; i += 256) Ks[i] = Km[i];
    __syncthreads();
    const int lane = t & 63;
    const int n = blockIdx.x * 4 + (t >> 6);
    if (n >= n_nodes) return;
    float* row = out + (long)n * D;
    const float rv = row[lane];
    float acc = 0.f;
    #pragma unroll
    for (int d = 0; d < D; ++d) acc = fmaf(__shfl(rv, d), Ks[d * D + lane], acc);
    row[lane] = acc;
}

extern "C" void kernel_launch(void* const* d_in, const int* in_sizes, int n_in,
                              void* d_out, int out_size, void* d_ws, size_t ws_size,
                              hipStream_t stream) {
    const float* nodes = (const float*)d_in[0];
    const float* evals = (const float*)d_in[1];
    const float* Km    = (const float*)d_in[2];
    const int*   src   = (const int*)d_in[3];
    const int*   dst   = (const int*)d_in[4];
    float* out = (float*)d_out;

    const int n_nodes = in_sizes[0] / D;
    const int n_edges = in_sizes[1];
    const int n_waves = (n_edges + EPW - 1) / EPW;

    zero_kernel<<<2048, 256, 0, stream>>>((float4*)out, out_size / 4);

    const size_t p_bytes = (size_t)n_nodes * D * sizeof(ushort);
    if (ws_size >= p_bytes) {
        ushort* P = (ushort*)d_ws;
        const int gw = (n_nodes + 7) / 8;
        gemm_rows<<<(gw + 3) / 4, 256, 0, stream>>>(nodes, Km, P, n_nodes);
        scatter_packed<<<(n_waves + 3) / 4, 256, 0, stream>>>(
            P, evals, src, dst, out, n_edges);
    } else {
        scatter_simple_f32<<<(n_waves + 3) / 4, 256, 0, stream>>>(
            nodes, evals, src, dst, out, n_edges);
        project_inplace<<<(n_nodes + 3) / 4, 256, 0, stream>>>(out, Km, n_nodes);
    }
}

// Round 11
// 115.443 us; speedup vs baseline: 1.1161x; 1.0608x over previous
//
#include <hip/hip_runtime.h>
#include <hip/hip_bf16.h>

// GCN layer on MI355X.
// out[n] = (segment_sum over edges e with dst[e]==n of w[e]*nodes[src[e]]) @ K
// Linearity: out = segment_sum(w[e] * P[src[e]] -> dst[e]),  P = nodes @ K.
// N=65536, E=1048576 (dst SORTED), D=UNITS=64.
//
// Round-11: MAX-MLP scatter. Cross-round evidence: aggregation time (~46us) is
// invariant to gather bytes (r4/r6), VMEM instr count (r10), wave count (r9).
// The invariant is per-wave MLP (~16) + serial s_load idx chains between
// 16-edge blocks -> latency-bound at ~10-20 outstanding misses/CU.
//  - scatter_deep: EPW=64/wave. Indices via 3 coalesced VGPR loads (no s_load
//    chain); run-boundary bitmap via one shfl_up+ballot (r10-verified logic);
//    ALL 64 row-gathers issued back-to-back (readlane row -> saddr ushort
//    load) = ~60 outstanding/wave; consume drains in issue order (rolling
//    vmcnt). Interior runs = plain store (exclusive ownership from sorted
//    dst), boundary runs (first / final) = atomicAdd onto zeroed out.
//  - gemm_rows (unchanged, r8-proven): lane=unit, K col in VGPRs, A-row via
//    readfirstlane->s_load.
//  - harness re-poison fills (~48us: 256MiB d_ws + 16MB out) are in the timed
//    path - fixed floor.

constexpr int D = 64;
constexpr int EPW = 64;   // edges per wave (E/EPW = 16384 waves)

__global__ __launch_bounds__(256) void zero_kernel(float4* __restrict__ p, int n4) {
    int i = blockIdx.x * blockDim.x + threadIdx.x;
    int stride = gridDim.x * blockDim.x;
    for (; i < n4; i += stride) p[i] = make_float4(0.f, 0.f, 0.f, 0.f);
}

// P_bf16 = bf16(nodes @ K).  One wave per 8 rows; lane = output unit.
__global__ __launch_bounds__(256) void gemm_rows(const float* __restrict__ nodes,
                                                 const float* __restrict__ Km,
                                                 ushort* __restrict__ P,
                                                 int n_nodes) {
    const int lane = threadIdx.x & 63;
    float kcol[D];
    #pragma unroll
    for (int d = 0; d < D; ++d) kcol[d] = Km[d * D + lane];

    const int wid = (blockIdx.x * blockDim.x + threadIdx.x) >> 6;
    const int urow0 = __builtin_amdgcn_readfirstlane(wid * 8);

    #pragma unroll 1
    for (int i = 0; i < 8; ++i) {
        const int row = urow0 + i;                 // uniform
        if (row >= n_nodes) return;
        const float4* rp = (const float4*)(nodes + (long)row * D);  // uniform addr
        float4 a[16];
        #pragma unroll
        for (int q = 0; q < 16; ++q) a[q] = rp[q]; // -> s_load
        const float* af = (const float*)a;
        float acc0 = 0.f, acc1 = 0.f, acc2 = 0.f, acc3 = 0.f;
        #pragma unroll
        for (int d = 0; d < D; d += 4) {
            acc0 = fmaf(af[d + 0], kcol[d + 0], acc0);
            acc1 = fmaf(af[d + 1], kcol[d + 1], acc1);
            acc2 = fmaf(af[d + 2], kcol[d + 2], acc2);
            acc3 = fmaf(af[d + 3], kcol[d + 3], acc3);
        }
        const float acc = (acc0 + acc1) + (acc2 + acc3);
        __hip_bfloat16 b = __float2bfloat16(acc);
        P[(long)row * D + lane] = *(ushort*)&b;    // coalesced 128B store
    }
}

// One wave per 64-edge chunk; lane = feature. All 64 gathers in flight at once.
__global__ __launch_bounds__(256) void scatter_deep(
    const ushort* __restrict__ P, const float* __restrict__ evals,
    const int* __restrict__ src, const int* __restrict__ dst,
    float* __restrict__ out, int n_edges)
{
    const int lane = threadIdx.x & 63;
    const int wid  = blockIdx.x * (blockDim.x >> 6) + (threadIdx.x >> 6);
    const long base = (long)wid * EPW;
    if (base >= n_edges) return;

    if (base + EPW <= n_edges) {
        // whole chunk's edge stream in 3 coalesced loads (256B each)
        const int   svl = src[base + lane];
        const int   dvl = dst[base + lane];
        const float wvl = evals[base + lane];

        // run-boundary bitmap: bit j set iff edge j starts a new run (j>0)
        const int dprev = __shfl_up(dvl, 1);
        const unsigned long long bmask = __ballot(lane > 0 && dvl != dprev);

        // issue ALL 64 row-gathers back-to-back (~60 outstanding, vmcnt-capped)
        unsigned raw[EPW];
        #pragma unroll
        for (int j = 0; j < EPW; ++j) {
            const int row = __builtin_amdgcn_readlane(svl, j);   // SGPR row
            raw[j] = P[(long)row * D + lane];  // global_load_ushort (saddr+lane*2)
        }

        const int first = __builtin_amdgcn_readlane(dvl, 0);
        int prev = first;
        float acc = 0.f;
        #pragma unroll
        for (int j = 0; j < EPW; ++j) {
            if ((bmask >> j) & 1ull) {          // uniform (SGPR) test -> scalar branch
                float* o = &out[(long)prev * D + lane];
                if (prev == first) atomicAdd(o, acc);   // run may span prev chunk
                else               *o = acc;            // exclusively owned run
                acc = 0.f;
                prev = __builtin_amdgcn_readlane(dvl, j);
            }
            const float w =
                __uint_as_float(__builtin_amdgcn_readlane(__float_as_uint(wvl), j));
            acc = fmaf(w, __uint_as_float(raw[j] << 16), acc);  // bf16 -> f32
        }
        atomicAdd(&out[(long)prev * D + lane], acc);    // run may span next chunk
    } else {
        // tail chunk (unused when EPW | n_edges)
        for (long e = base; e < n_edges; ++e) {
            const float pv =
                __uint_as_float(((unsigned)P[(long)src[e] * D + lane]) << 16);
            atomicAdd(&out[(long)dst[e] * D + lane], evals[e] * pv);
        }
    }
}

// ---------------- fallback path (d_ws too small): f32 scatter + projection ----
__global__ __launch_bounds__(256) void scatter_simple_f32(
    const float* __restrict__ nodes, const float* __restrict__ evals,
    const int* __restrict__ src, const int* __restrict__ dst,
    float* __restrict__ out, int n_edges)
{
    const int lane = threadIdx.x & 63;
    const int wid  = blockIdx.x * (blockDim.x >> 6) + (threadIdx.x >> 6);
    const long base = (long)wid * 128;
    if (base >= n_edges) return;
    long end = base + 128; if (end > n_edges) end = n_edges;
    for (long e = base; e < end; ++e)
        atomicAdd(&out[(long)dst[e] * D + lane], evals[e] * nodes[(long)src[e] * D + lane]);
}

__global__ __launch_bounds__(256) void project_inplace(float* __restrict__ out,
                                                       const float* __restrict__ Km, int n_nodes) {
    __shared__ float Ks[D * D];
    const int t = threadIdx.x;
    for (int i = t; i < D * D; i += 256) Ks[i] = Km[i];
    __syncthreads();
    const int lane = t & 63;
    const int n = blockIdx.x * 4 + (t >> 6);
    if (n >= n_nodes) return;
    float* row = out + (long)n * D;
    const float rv = row[lane];
    float acc = 0.f;
    #pragma unroll
    for (int d = 0; d < D; ++d) acc = fmaf(__shfl(rv, d), Ks[d * D + lane], acc);
    row[lane] = acc;
}

extern "C" void kernel_launch(void* const* d_in, const int* in_sizes, int n_in,
                              void* d_out, int out_size, void* d_ws, size_t ws_size,
                              hipStream_t stream) {
    const float* nodes = (const float*)d_in[0];
    const float* evals = (const float*)d_in[1];
    const float* Km    = (const float*)d_in[2];
    const int*   src   = (const int*)d_in[3];
    const int*   dst   = (const int*)d_in[4];
    float* out = (float*)d_out;

    const int n_nodes = in_sizes[0] / D;
    const int n_edges = in_sizes[1];
    const int n_waves = (n_edges + EPW - 1) / EPW;

    zero_kernel<<<2048, 256, 0, stream>>>((float4*)out, out_size / 4);

    const size_t p_bytes = (size_t)n_nodes * D * sizeof(ushort);
    if (ws_size >= p_bytes) {
        ushort* P = (ushort*)d_ws;
        const int gw = (n_nodes + 7) / 8;
        gemm_rows<<<(gw + 3) / 4, 256, 0, stream>>>(nodes, Km, P, n_nodes);
        scatter_deep<<<(n_waves + 3) / 4, 256, 0, stream>>>(
            P, evals, src, dst, out, n_edges);
    } else {
        const int fw = (n_edges + 127) / 128;
        scatter_simple_f32<<<(fw + 3) / 4, 256, 0, stream>>>(
            nodes, evals, src, dst, out, n_edges);
        project_inplace<<<(n_nodes + 3) / 4, 256, 0, stream>>>(out, Km, n_nodes);
    }
}